// Round 8
// baseline (317.492 us; speedup 1.0000x reference)
//
#include <hip/hip_runtime.h>

// ---------------------------------------------------------------------------
// LiteMLA: B=4, N=4096, C=1024, D=32, h=32 heads.
//   qkv = x @ W_qkv^T            (16384 x 3072, K=1024)   [relu on q,k cols]
//   per (b,h): vk[d,e] = sum_n Vpad[d,n]*reluK[e,n]   (33x32, reduce N=4096)
//              y[d,n]  = (sum_e vk[d,e]*reluQ[e,n]) / (sum_e vk[32,e]*reluQ[e,n] + eps)
//   out = y @ W_proj^T + b_proj  (16384 x 1024, K=1024)
//
// GEMM (R7 core, kept): 256x256 tile, 8 waves (128x64/wave), BK=32,
// 3 x 32KB LDS buffers, 1 barrier + 1 counted vmcnt(4) per K-tile.
// R1-R7 established ~110us / 40% MfmaUtil as the schedule-insensitive
// plateau for this GEMM (LDS-port work ~2800cyc/tile + MFMA ~2480cyc/tile
// serialize under fair port arbitration regardless of barrier density).
// R8 micro-reorder: STAGE issued before frag reads (DMA issue ahead of the
// 12 ds_reads); vmcnt(4) invariant unchanged (outstanding 8 -> retire to 4
// = tile g+1's loads). Numerics identical (accumulation order unchanged).
//
// R8 main change: lite_vk atomics removed. Each (bh, ck) block now stores
// its partial vk to vkws[ck][bh][1056] (plain stores, no zero-init, no
// 1M device-scope atomicAdds); lite_apply sums the 8 ck-partials while
// building its LDS copy (vkws = 4.3MB, L2-resident; +33KB reads/block).
// prep no longer zeroes vkws.
// ---------------------------------------------------------------------------

using us8   = __attribute__((ext_vector_type(8))) unsigned short;
using us4   = __attribute__((ext_vector_type(4))) unsigned short;
using s8v   = __attribute__((ext_vector_type(8))) short;
using f32x4 = __attribute__((ext_vector_type(4))) float;

__device__ __forceinline__ unsigned short f2bf(float f) {
    union { float f; unsigned int u; } c; c.f = f;
    unsigned int r = c.u + 0x7fffu + ((c.u >> 16) & 1u);   // RTN-even
    return (unsigned short)(r >> 16);
}
__device__ __forceinline__ float bf2f(unsigned short u) {
    union { unsigned int u; float f; } c; c.u = ((unsigned int)u) << 16;
    return c.f;
}

// async global->LDS, 16B per lane; LDS dest = wave-uniform base + lane*16
__device__ __forceinline__ void async16(const unsigned short* g, unsigned short* l) {
    __builtin_amdgcn_global_load_lds(
        (const __attribute__((address_space(1))) unsigned int*)g,
        (__attribute__((address_space(3))) unsigned int*)l, 16, 0, 0);
}

// ------------------------ fused fp32->bf16 converts ------------------------
__global__ __launch_bounds__(256)
void prep(const float* __restrict__ x, const float* __restrict__ wq,
          const float* __restrict__ wp, unsigned short* __restrict__ xb,
          unsigned short* __restrict__ wqb, unsigned short* __restrict__ wpb) {
    const int NX = 16777216 / 8, NQ = 3145728 / 8, NP = 1048576 / 8;
    int gid = blockIdx.x * 256 + threadIdx.x;
    const float* in; unsigned short* out; int i;
    if (gid < NX)                { in = x;  out = xb;  i = gid * 8; }
    else if (gid < NX + NQ)      { in = wq; out = wqb; i = (gid - NX) * 8; }
    else if (gid < NX + NQ + NP) { in = wp; out = wpb; i = (gid - NX - NQ) * 8; }
    else return;
    float4 a = *(const float4*)(in + i);
    float4 b = *(const float4*)(in + i + 4);
    us8 o;
    o[0] = f2bf(a.x); o[1] = f2bf(a.y); o[2] = f2bf(a.z); o[3] = f2bf(a.w);
    o[4] = f2bf(b.x); o[5] = f2bf(b.y); o[6] = f2bf(b.z); o[7] = f2bf(b.w);
    *(us8*)(out + i) = o;
}

// --------------- 256x256 / BK=32 / sparse-barrier GEMM core ----------------
constexpr int TSZ = 16384;               // elems per buffer (A 8192 + B 8192)

#define FENCE() asm volatile("" ::: "memory")
#define BARX()  do { FENCE(); __builtin_amdgcn_s_barrier(); FENCE(); } while (0)

// stage one K-tile (A 256x32 + B 256x32) into buffer BS: 4 async16/thread.
#define STAGE(KT, BS)                                                        \
  do {                                                                       \
    async16(Ag + g0 + (KT), (BS) + d0);                                      \
    async16(Ag + g1 + (KT), (BS) + d1);                                      \
    async16(Bg + g0 + (KT), (BS) + 8192 + d0);                               \
    async16(Bg + g1 + (KT), (BS) + 8192 + d1);                               \
  } while (0)

// MODE 0: cols<1024 -> Q token-major bf16 (relu); cols>=1024 -> kvT.
// MODE 1: fp32 + bias.
template <int MODE>
__device__ __forceinline__
void gemm_core256(const unsigned short* __restrict__ A,
                  const unsigned short* __restrict__ Bt,
                  unsigned short* __restrict__ Cq,
                  unsigned short* __restrict__ kvT,
                  float* __restrict__ Cf, const float* __restrict__ bias,
                  int N, int tM, int tN, unsigned short* lds) {
    const int t    = threadIdx.x;
    const int lane = t & 63;
    const int wv   = t >> 6;
    const int wr   = wv >> 2;                 // 0..1 : A 128-row slab
    const int wc   = wv & 3;                  // 0..3 : 64-col slab
    const int mrow = lane & 15;
    const int kq   = lane >> 4;               // 0..3

    // staging decode: chunk c -> row r = c>>2, phys slot sp = c&3,
    // source k-quad = sp ^ ((r>>1)&3)  (involution with read swizzle)
    const int c0 = t, c1 = 512 + t;
    const int r0 = c0 >> 2, r1 = c1 >> 2;
    const int g0 = r0 * 1024 + ((c0 & 3) ^ ((r0 >> 1) & 3)) * 8;
    const int g1 = r1 * 1024 + ((c1 & 3) ^ ((r1 >> 1) & 3)) * 8;
    const unsigned short* Ag = A  + (size_t)tM * 1024;
    const unsigned short* Bg = Bt + (size_t)tN * 1024;
    const int d0 = wv * 512, d1 = 4096 + wv * 512;   // elems in operand half

    // ds_read offsets: swz invariant across mi/ni
    const int swz  = (kq ^ ((mrow >> 1) & 3)) * 8;
    const int aoff = (wr * 128 + mrow) * 32 + swz;    // + mi*512
    const int boff = (wc * 64  + mrow) * 32 + swz;    // + ni*512, +8192 base

    f32x4 acc[8][4] = {};
    s8v af[8], bf[4];

    constexpr int NT = 32;                    // K = 1024 = 32 x 32

    // prologue: tiles 0,1 -> buf0,buf1; vmcnt(4) retires tile0's 4 loads
    STAGE(0,  lds);
    STAGE(32, lds + TSZ);
    asm volatile("s_waitcnt vmcnt(4)" ::: "memory");
    BARX();

    unsigned short* bR = lds;                 // read  : tile g
    unsigned short* bT = lds + TSZ;           // ready : tile g+1
    unsigned short* bS = lds + 2 * TSZ;       // stage : tile g+2

    for (int g = 0; g < NT; ++g) {
        const int kt = (g + 2 < NT ? g + 2 : NT - 1) * 32;
        STAGE(kt, bS);                        // DMA issue ahead of ds_reads
        FENCE();
#pragma unroll
        for (int mi = 0; mi < 8; ++mi)
            af[mi] = *(const s8v*)&bR[aoff + mi * 512];
#pragma unroll
        for (int ni = 0; ni < 4; ++ni)
            bf[ni] = *(const s8v*)&bR[8192 + boff + ni * 512];
        __builtin_amdgcn_s_setprio(1);
#pragma unroll
        for (int mi = 0; mi < 8; ++mi)
#pragma unroll
            for (int ni = 0; ni < 4; ++ni)
                acc[mi][ni] = __builtin_amdgcn_mfma_f32_16x16x32_bf16(
                    af[mi], bf[ni], acc[mi][ni], 0, 0, 0);
        __builtin_amdgcn_s_setprio(0);
        asm volatile("s_waitcnt vmcnt(4)" ::: "memory");  // retire stage(g+1)
        BARX();
        unsigned short* tmp = bR; bR = bT; bT = bS; bS = tmp;
    }

    // ----------------------------- epilogue --------------------------------
    const int crow0 = kq * 4;
    const int ccol  = mrow;
    if (MODE == 0) {
        if (tN >= 1024) {
            const int b2  = tM >> 12;
            const int nb0 = (tM & 4095) + wr * 128;
#pragma unroll
            for (int mi = 0; mi < 8; ++mi) {
                const int nbase = nb0 + mi * 16 + crow0;
#pragma unroll
                for (int ni = 0; ni < 4; ++ni) {
                    const int col = tN + wc * 64 + ni * 16 + ccol;
                    f32x4 v = acc[mi][ni];
                    if (col < 2048) {
                        v[0] = fmaxf(v[0], 0.f); v[1] = fmaxf(v[1], 0.f);
                        v[2] = fmaxf(v[2], 0.f); v[3] = fmaxf(v[3], 0.f);
                    }
                    us4 o;
                    o[0] = f2bf(v[0]); o[1] = f2bf(v[1]);
                    o[2] = f2bf(v[2]); o[3] = f2bf(v[3]);
                    *(us4*)&kvT[((size_t)b2 * 2048 + (col - 1024)) * 4096 + nbase] = o;
                }
            }
        } else {
#pragma unroll
            for (int mi = 0; mi < 8; ++mi)
#pragma unroll
                for (int ni = 0; ni < 4; ++ni) {
                    const int row = tM + wr * 128 + mi * 16 + crow0;
                    const int col = tN + wc * 64 + ni * 16 + ccol;
#pragma unroll
                    for (int r2 = 0; r2 < 4; ++r2)
                        Cq[(size_t)(row + r2) * 1024 + col] =
                            f2bf(fmaxf(acc[mi][ni][r2], 0.f));
                }
        }
    } else {
#pragma unroll
        for (int mi = 0; mi < 8; ++mi)
#pragma unroll
            for (int ni = 0; ni < 4; ++ni) {
                const int row = tM + wr * 128 + mi * 16 + crow0;
                const int col = tN + wc * 64 + ni * 16 + ccol;
#pragma unroll
                for (int r2 = 0; r2 < 4; ++r2)
                    Cf[(size_t)(row + r2) * N + col] = acc[mi][ni][r2] + bias[col];
            }
    }
    // drain LDS-DMA before wave exit (LDS may be re-allocated to next block)
    asm volatile("s_waitcnt vmcnt(0)" ::: "memory");
}

// XCD-aware tile map: xcd = blk&7 owns an 8-M-tile stripe; N swept in panels
// of 4 (B-panel 2 MB stays L2-hot), tN fastest within panel.
__device__ __forceinline__ void xcd_map256(int blk, int MT, int& tM, int& tN) {
    const int xcd = blk & 7;
    const int i   = blk >> 3;
    const int MTx = MT >> 3;             // M-tiles per XCD (8)
    const int ppan = MTx * 4;            // blocks per 4-wide panel per XCD
    const int p   = i / ppan;
    const int i2  = i % ppan;
    tM = (xcd * MTx + (i2 >> 2)) * 256;
    tN = (p * 4 + (i2 & 3)) * 256;
}

__global__ __launch_bounds__(512, 2)
void gemm_qkv(const unsigned short* __restrict__ A,
              const unsigned short* __restrict__ Bt,
              unsigned short* __restrict__ Cq, unsigned short* __restrict__ kvT,
              int M, int N) {
    extern __shared__ unsigned short lds[];
    int tM, tN;
    xcd_map256(blockIdx.x, M >> 8, tM, tN);
    gemm_core256<0>(A, Bt, Cq, kvT, nullptr, nullptr, N, tM, tN, lds);
}

__global__ __launch_bounds__(512, 2)
void gemm_proj(const unsigned short* __restrict__ A,
               const unsigned short* __restrict__ Bt,
               float* __restrict__ C, const float* __restrict__ bias,
               int M, int N) {
    extern __shared__ unsigned short lds[];
    int tM, tN;
    xcd_map256(blockIdx.x, M >> 8, tM, tN);
    gemm_core256<1>(A, Bt, nullptr, nullptr, C, bias, N, tM, tN, lds);
}

// ------ vk = Vpad @ reluK^T via MFMA over kvT (partials, no atomics) -------
__global__ __launch_bounds__(256)
void lite_vk(const unsigned short* __restrict__ kvT, float* __restrict__ vkws) {
    const int bh = blockIdx.x, ck = blockIdx.y;
    const int b = bh >> 5, h = bh & 31;
    const int S = 136;
    __shared__ unsigned short Ks[32 * S];
    __shared__ unsigned short Vs[32 * S];
    __shared__ float Rs[4][1088];
    const int t = threadIdx.x, lane = t & 63, wv = t >> 6;
    const unsigned short* Kp = kvT + ((size_t)b * 2048 + h * 32) * 4096 + ck * 512;
    const unsigned short* Vp = kvT + ((size_t)b * 2048 + 1024 + h * 32) * 4096 + ck * 512;
    const int sr = t >> 3, ss = (t & 7) * 16;
    f32x4 acc00 = {}, acc01 = {}, acc10 = {}, acc11 = {}, accO0 = {}, accO1 = {};
    s8v ones;
#pragma unroll
    for (int j = 0; j < 8; ++j) ones[j] = (short)0x3F80;
    const int mrow = lane & 15, kq = (lane >> 4) * 8;

    for (int tile = 0; tile < 4; ++tile) {
        int go = tile * 128 + ss;
        us8 k0v = *(const us8*)(Kp + (size_t)sr * 4096 + go);
        us8 k1v = *(const us8*)(Kp + (size_t)sr * 4096 + go + 8);
        us8 v0v = *(const us8*)(Vp + (size_t)sr * 4096 + go);
        us8 v1v = *(const us8*)(Vp + (size_t)sr * 4096 + go + 8);
        __syncthreads();
        *(us8*)&Ks[sr * S + ss]     = k0v;
        *(us8*)&Ks[sr * S + ss + 8] = k1v;
        *(us8*)&Vs[sr * S + ss]     = v0v;
        *(us8*)&Vs[sr * S + ss + 8] = v1v;
        __syncthreads();
        int ko = wv * 32 + kq;
        s8v a0 = *(const s8v*)&Vs[(mrow)      * S + ko];
        s8v a1 = *(const s8v*)&Vs[(16 + mrow) * S + ko];
        s8v b0 = *(const s8v*)&Ks[(mrow)      * S + ko];
        s8v b1 = *(const s8v*)&Ks[(16 + mrow) * S + ko];
        acc00 = __builtin_amdgcn_mfma_f32_16x16x32_bf16(a0, b0, acc00, 0, 0, 0);
        acc01 = __builtin_amdgcn_mfma_f32_16x16x32_bf16(a0, b1, acc01, 0, 0, 0);
        acc10 = __builtin_amdgcn_mfma_f32_16x16x32_bf16(a1, b0, acc10, 0, 0, 0);
        acc11 = __builtin_amdgcn_mfma_f32_16x16x32_bf16(a1, b1, acc11, 0, 0, 0);
        accO0 = __builtin_amdgcn_mfma_f32_16x16x32_bf16(ones, b0, accO0, 0, 0, 0);
        accO1 = __builtin_amdgcn_mfma_f32_16x16x32_bf16(ones, b1, accO1, 0, 0, 0);
    }

    const int ccol = lane & 15, crow = (lane >> 4) * 4;
    float* R = Rs[wv];
#pragma unroll
    for (int r2 = 0; r2 < 4; ++r2) {
        R[(crow + r2) * 32 + ccol]           = acc00[r2];
        R[(crow + r2) * 32 + 16 + ccol]      = acc01[r2];
        R[(16 + crow + r2) * 32 + ccol]      = acc10[r2];
        R[(16 + crow + r2) * 32 + 16 + ccol] = acc11[r2];
    }
    if ((lane >> 4) == 0) {
        R[1024 + ccol]      = accO0[0];
        R[1024 + 16 + ccol] = accO1[0];
    }
    __syncthreads();
    // partial store: vkws[ck][bh][1056], plain stores (no atomics, no zero)
    float* vkb = vkws + ((size_t)ck * 128 + bh) * 1056;
    for (int i = t; i < 1056; i += 256) {
        vkb[i] = Rs[0][i] + Rs[1][i] + Rs[2][i] + Rs[3][i];
    }
}

// --------------- y = (vk @ reluQ) / pad-row, MFMA K=32 ---------------------
__global__ __launch_bounds__(256)
void lite_apply(const unsigned short* __restrict__ qb,
                const float* __restrict__ vkws,
                unsigned short* __restrict__ yb) {
    const int bh = blockIdx.x, nb = blockIdx.y;
    const int b = bh >> 5, h = bh & 31;
    __shared__ unsigned short vkh[48 * 32];
    __shared__ unsigned short vkl[48 * 32];
    const int t = threadIdx.x;
    for (int i = t; i < 48 * 32; i += 256) {
        float v = 0.f;
        if (i < 33 * 32) {
#pragma unroll
            for (int p = 0; p < 8; ++p)
                v += vkws[((size_t)p * 128 + bh) * 1056 + i];
        }
        unsigned short hi = f2bf(v);
        vkh[i] = hi;
        vkl[i] = f2bf(v - bf2f(hi));
    }
    __syncthreads();

    const int lane = t & 63, wv = t >> 6;
    const int col = lane & 15, quad = lane >> 4;
    s8v b0h = *(const s8v*)&vkh[(col)      * 32 + quad * 8];
    s8v b0l = *(const s8v*)&vkl[(col)      * 32 + quad * 8];
    s8v b1h = *(const s8v*)&vkh[(16 + col) * 32 + quad * 8];
    s8v b1l = *(const s8v*)&vkl[(16 + col) * 32 + quad * 8];
    s8v b2h = *(const s8v*)&vkh[(32 + col) * 32 + quad * 8];
    s8v b2l = *(const s8v*)&vkl[(32 + col) * 32 + quad * 8];

    const int ntile = nb * 256 + wv * 64;
#pragma unroll
    for (int mi = 0; mi < 4; ++mi) {
        int tok = ntile + mi * 16 + col;
        const unsigned short* qp =
            qb + (size_t)(b * 4096 + tok) * 1024 + h * 32 + quad * 8;
        s8v a = *(const s8v*)qp;
        f32x4 n0 = {}, n1 = {}, dd = {};
        n0 = __builtin_amdgcn_mfma_f32_16x16x32_bf16(b0h, a, n0, 0, 0, 0);
        n0 = __builtin_amdgcn_mfma_f32_16x16x32_bf16(b0l, a, n0, 0, 0, 0);
        n1 = __builtin_amdgcn_mfma_f32_16x16x32_bf16(b1h, a, n1, 0, 0, 0);
        n1 = __builtin_amdgcn_mfma_f32_16x16x32_bf16(b1l, a, n1, 0, 0, 0);
        dd = __builtin_amdgcn_mfma_f32_16x16x32_bf16(b2h, a, dd, 0, 0, 0);
        dd = __builtin_amdgcn_mfma_f32_16x16x32_bf16(b2l, a, dd, 0, 0, 0);
        float den  = __shfl(dd[0], col, 64);
        float rinv = 1.f / (den + 1e-15f);
        us4 o0, o1;
#pragma unroll
        for (int r = 0; r < 4; ++r) {
            o0[r] = f2bf(n0[r] * rinv);
            o1[r] = f2bf(n1[r] * rinv);
        }
        size_t o = (size_t)(b * 4096 + tok) * 1024 + h * 32;
        *(us4*)&yb[o + quad * 4]      = o0;
        *(us4*)&yb[o + 16 + quad * 4] = o1;
    }
}

// ---------------------------------------------------------------------------
extern "C" void kernel_launch(void* const* d_in, const int* in_sizes, int n_in,
                              void* d_out, int out_size, void* d_ws, size_t ws_size,
                              hipStream_t stream) {
    const float* x     = (const float*)d_in[0];   // (4,4096,1024)
    const float* Wqkv  = (const float*)d_in[1];   // (3072,1024)
    const float* Wproj = (const float*)d_in[2];   // (1024,1024)
    const float* bproj = (const float*)d_in[3];   // (1024,)
    float* out = (float*)d_out;                   // (4,4096,1024) fp32

    const int M = 16384, Cdim = 1024, O1 = 3072;

    unsigned short* xb     = (unsigned short*)d_ws;
    unsigned short* wqkvb  = xb + (size_t)M * Cdim;
    unsigned short* wprojb = wqkvb + (size_t)O1 * Cdim;
    unsigned short* qb     = wprojb + (size_t)Cdim * Cdim;        // Q token-major
    unsigned short* kvT    = qb + (size_t)M * Cdim;               // [4][2048][4096]
    unsigned short* ybuf   = kvT + (size_t)4 * 2048 * 4096;
    float* vkws            = (float*)(ybuf + (size_t)M * Cdim);   // [8][128][1056]
    // ws use: ~180 MB

    static int attr_done = 0;
    if (!attr_done) {
        hipFuncSetAttribute((const void*)gemm_qkv,
                            hipFuncAttributeMaxDynamicSharedMemorySize, 98304);
        hipFuncSetAttribute((const void*)gemm_proj,
                            hipFuncAttributeMaxDynamicSharedMemorySize, 98304);
        attr_done = 1;
    }

    const int PREP_GROUPS = (16777216 + 3145728 + 1048576) / 8;
    prep<<<(PREP_GROUPS + 255) / 256, 256, 0, stream>>>(
        x, Wqkv, Wproj, xb, wqkvb, wprojb);

    gemm_qkv<<<(M / 256) * (O1 / 256), 512, 98304, stream>>>(
        xb, wqkvb, qb, kvT, M, O1);

    lite_vk<<<dim3(128, 8), 256, 0, stream>>>(kvT, vkws);
    lite_apply<<<dim3(128, 16), 256, 0, stream>>>(qb, vkws, ybuf);

    gemm_proj<<<(M / 256) * (Cdim / 256), 512, 98304, stream>>>(
        ybuf, wprojb, out, bproj, M, Cdim);
}

// Round 9
// 301.079 us; speedup vs baseline: 1.0545x; 1.0545x over previous
//
#include <hip/hip_runtime.h>

// ---------------------------------------------------------------------------
// LiteMLA: B=4, N=4096, C=1024, D=32, h=32 heads.
//   qkv = x @ W_qkv^T            (16384 x 3072, K=1024)   [relu on q,k cols]
//   per (b,h): vk[d,e] = sum_n Vpad[d,n]*reluK[e,n]   (33x32, reduce N=4096)
//              y[d,n]  = (sum_e vk[d,e]*reluQ[e,n]) / (sum_e vk[32,e]*reluQ[e,n] + eps)
//   out = y @ W_proj^T + b_proj  (16384 x 1024, K=1024)
//
// R9: vk FUSED into gemm_qkv epilogue; lite_vk + kvT (64MB write + 64MB
// read) eliminated. prep permutes W_qkv rows >=1024 so each 64-col group =
// one head's K(0..31)+V(32..63); a wave's 128x64 acc patch = 128 tokens x
// one head. Epilogue: per-wave 12KB LDS transpose (XOR-swizzled [ch][128n],
// involution write/read), 24 MFMAs -> 33x32 partial -> vkp[p][bh] plain
// stores (p = token-chunk*2 + wr, 32 partials/bh, each written once).
// lite_apply sums 32 partials (17MB vkp, L2-resident).
// GEMM core = R7 verbatim (BK=32, 3x32KB bufs, 1 barrier + vmcnt(4)/tile) —
// the 108-112us / ~40% MfmaUtil plateau proved schedule-insensitive R1-R8.
// Numerics: K/V bf16-rounded exactly as old kvT; only fp32 sum order of vk
// changes (noise ~1e-6 << passing absmax 2.4e-4).
// ---------------------------------------------------------------------------

using us8   = __attribute__((ext_vector_type(8))) unsigned short;
using us4   = __attribute__((ext_vector_type(4))) unsigned short;
using s8v   = __attribute__((ext_vector_type(8))) short;
using f32x4 = __attribute__((ext_vector_type(4))) float;

__device__ __forceinline__ unsigned short f2bf(float f) {
    union { float f; unsigned int u; } c; c.f = f;
    unsigned int r = c.u + 0x7fffu + ((c.u >> 16) & 1u);   // RTN-even
    return (unsigned short)(r >> 16);
}
__device__ __forceinline__ float bf2f(unsigned short u) {
    union { unsigned int u; float f; } c; c.u = ((unsigned int)u) << 16;
    return c.f;
}

// async global->LDS, 16B per lane; LDS dest = wave-uniform base + lane*16
__device__ __forceinline__ void async16(const unsigned short* g, unsigned short* l) {
    __builtin_amdgcn_global_load_lds(
        (const __attribute__((address_space(1))) unsigned int*)g,
        (__attribute__((address_space(3))) unsigned int*)l, 16, 0, 0);
}

// ---------- fused fp32->bf16 converts; W_qkv rows >=1024 permuted ----------
// K row 1024+h*32+d -> 1024+h*64+d ; V row 2048+h*32+d -> 1024+h*64+32+d
__global__ __launch_bounds__(256)
void prep(const float* __restrict__ x, const float* __restrict__ wq,
          const float* __restrict__ wp, unsigned short* __restrict__ xb,
          unsigned short* __restrict__ wqb, unsigned short* __restrict__ wpb) {
    const int NX = 16777216 / 8, NQ = 3145728 / 8, NP = 1048576 / 8;
    int gid = blockIdx.x * 256 + threadIdx.x;
    const float* in; unsigned short* out; int i, oi;
    if (gid < NX)                { in = x;  out = xb;  i = gid * 8; oi = i; }
    else if (gid < NX + NQ) {
        i = (gid - NX) * 8;
        int r = i >> 10, cc = i & 1023, rp;
        if (r < 1024)      rp = r;
        else if (r < 2048) rp = 1024 + ((r - 1024) >> 5) * 64 + (r & 31);
        else               rp = 1056 + ((r - 2048) >> 5) * 64 + (r & 31);
        in = wq; out = wqb; oi = rp * 1024 + cc;
    }
    else if (gid < NX + NQ + NP) { in = wp; out = wpb; i = (gid - NX - NQ) * 8; oi = i; }
    else return;
    float4 a = *(const float4*)(in + i);
    float4 b = *(const float4*)(in + i + 4);
    us8 o;
    o[0] = f2bf(a.x); o[1] = f2bf(a.y); o[2] = f2bf(a.z); o[3] = f2bf(a.w);
    o[4] = f2bf(b.x); o[5] = f2bf(b.y); o[6] = f2bf(b.z); o[7] = f2bf(b.w);
    *(us8*)(out + oi) = o;
}

// --------------- 256x256 / BK=32 / sparse-barrier GEMM core ----------------
constexpr int TSZ = 16384;               // elems per buffer (A 8192 + B 8192)

#define FENCE() asm volatile("" ::: "memory")
#define BARX()  do { FENCE(); __builtin_amdgcn_s_barrier(); FENCE(); } while (0)

// stage one K-tile (A 256x32 + B 256x32) into buffer BS: 4 async16/thread.
#define STAGE(KT, BS)                                                        \
  do {                                                                       \
    async16(Ag + g0 + (KT), (BS) + d0);                                      \
    async16(Ag + g1 + (KT), (BS) + d1);                                      \
    async16(Bg + g0 + (KT), (BS) + 8192 + d0);                               \
    async16(Bg + g1 + (KT), (BS) + 8192 + d1);                               \
  } while (0)

// MODE 0: cols<1024 -> Q token-major bf16 (relu); cols>=1024 -> fused vk.
// MODE 1: fp32 + bias.
template <int MODE>
__device__ __forceinline__
void gemm_core256(const unsigned short* __restrict__ A,
                  const unsigned short* __restrict__ Bt,
                  unsigned short* __restrict__ Cq,
                  float* __restrict__ vkp,
                  float* __restrict__ Cf, const float* __restrict__ bias,
                  int N, int tM, int tN, unsigned short* lds) {
    const int t    = threadIdx.x;
    const int lane = t & 63;
    const int wv   = t >> 6;
    const int wr   = wv >> 2;                 // 0..1 : A 128-row slab
    const int wc   = wv & 3;                  // 0..3 : 64-col slab
    const int mrow = lane & 15;
    const int kq   = lane >> 4;               // 0..3

    // staging decode (R7-verified involution with read swizzle)
    const int c0 = t, c1 = 512 + t;
    const int r0 = c0 >> 2, r1 = c1 >> 2;
    const int g0 = r0 * 1024 + ((c0 & 3) ^ ((r0 >> 1) & 3)) * 8;
    const int g1 = r1 * 1024 + ((c1 & 3) ^ ((r1 >> 1) & 3)) * 8;
    const unsigned short* Ag = A  + (size_t)tM * 1024;
    const unsigned short* Bg = Bt + (size_t)tN * 1024;
    const int d0 = wv * 512, d1 = 4096 + wv * 512;   // elems in operand half

    // ds_read offsets: swz invariant across mi/ni
    const int swz  = (kq ^ ((mrow >> 1) & 3)) * 8;
    const int aoff = (wr * 128 + mrow) * 32 + swz;    // + mi*512
    const int boff = (wc * 64  + mrow) * 32 + swz;    // + ni*512, +8192 base

    f32x4 acc[8][4] = {};
    s8v af[8], bf[4];

    constexpr int NT = 32;                    // K = 1024 = 32 x 32

    // prologue: tiles 0,1 -> buf0,buf1; vmcnt(4) retires tile0's 4 loads
    STAGE(0,  lds);
    STAGE(32, lds + TSZ);
    asm volatile("s_waitcnt vmcnt(4)" ::: "memory");
    BARX();

    unsigned short* bR = lds;                 // read  : tile g
    unsigned short* bT = lds + TSZ;           // ready : tile g+1
    unsigned short* bS = lds + 2 * TSZ;       // stage : tile g+2

    for (int g = 0; g < NT; ++g) {
        const int kt = (g + 2 < NT ? g + 2 : NT - 1) * 32;
#pragma unroll
        for (int mi = 0; mi < 8; ++mi)
            af[mi] = *(const s8v*)&bR[aoff + mi * 512];
#pragma unroll
        for (int ni = 0; ni < 4; ++ni)
            bf[ni] = *(const s8v*)&bR[8192 + boff + ni * 512];
        STAGE(kt, bS);
        __builtin_amdgcn_s_setprio(1);
#pragma unroll
        for (int mi = 0; mi < 8; ++mi)
#pragma unroll
            for (int ni = 0; ni < 4; ++ni)
                acc[mi][ni] = __builtin_amdgcn_mfma_f32_16x16x32_bf16(
                    af[mi], bf[ni], acc[mi][ni], 0, 0, 0);
        __builtin_amdgcn_s_setprio(0);
        asm volatile("s_waitcnt vmcnt(4)" ::: "memory");  // retire stage(g+1)
        BARX();
        unsigned short* tmp = bR; bR = bT; bT = bS; bS = tmp;
    }

    // drain all LDS-DMA and sync: LDS is reused below / freed on exit
    asm volatile("s_waitcnt vmcnt(0)" ::: "memory");
    BARX();

    // ----------------------------- epilogue --------------------------------
    const int crow0 = kq * 4;
    const int ccol  = mrow;
    if (MODE == 0) {
        if (tN >= 1024) {
            // ---- fused vk: wave patch = 128 tokens x head (K 0..31|V 32..63)
            unsigned short* usW = lds + wv * 6144;   // Kt[32][128] + Vh[16][128]
            // write relu'd K (ni 0,1) and V d-half 0 (ni=2, d=mrow)
#pragma unroll
            for (int mi = 0; mi < 8; ++mi) {
                const int n0 = mi * 16 + kq * 4;
                const int sub = n0 & 7;
#pragma unroll
                for (int ni = 0; ni < 2; ++ni) {
                    const int e = ni * 16 + mrow;
                    us4 o;
#pragma unroll
                    for (int r2 = 0; r2 < 4; ++r2)
                        o[r2] = f2bf(fmaxf(acc[mi][ni][r2], 0.f));
                    *(us4*)&usW[e * 128 + (((n0 >> 3) ^ e) & 15) * 8 + sub] = o;
                }
                us4 ov;
#pragma unroll
                for (int r2 = 0; r2 < 4; ++r2)
                    ov[r2] = f2bf(acc[mi][2][r2]);
                *(us4*)&usW[4096 + mrow * 128 + (((n0 >> 3) ^ mrow) & 15) * 8 + sub] = ov;
            }
            FENCE();
            // K frags (both e-blocks, reused for both d-halves) + V frags
            s8v bK[2][4], aV[4], ones;
#pragma unroll
            for (int j = 0; j < 8; ++j) ones[j] = (short)0x3F80;
#pragma unroll
            for (int eblk = 0; eblk < 2; ++eblk)
#pragma unroll
                for (int ks = 0; ks < 4; ++ks) {
                    const int e = eblk * 16 + mrow;
                    bK[eblk][ks] = *(const s8v*)&usW[e * 128 + (((ks * 4 + kq) ^ mrow) & 15) * 8];
                }
#pragma unroll
            for (int ks = 0; ks < 4; ++ks)
                aV[ks] = *(const s8v*)&usW[4096 + mrow * 128 + (((ks * 4 + kq) ^ mrow) & 15) * 8];
            f32x4 vk0[2] = {}, vk1[2] = {}, pd[2] = {};
#pragma unroll
            for (int eblk = 0; eblk < 2; ++eblk)
#pragma unroll
                for (int ks = 0; ks < 4; ++ks) {
                    vk0[eblk] = __builtin_amdgcn_mfma_f32_16x16x32_bf16(
                        aV[ks], bK[eblk][ks], vk0[eblk], 0, 0, 0);
                    pd[eblk] = __builtin_amdgcn_mfma_f32_16x16x32_bf16(
                        ones, bK[eblk][ks], pd[eblk], 0, 0, 0);
                }
            FENCE();
            // V d-half 1 (ni=3, d = 16+mrow) overwrites Vh after reads done
#pragma unroll
            for (int mi = 0; mi < 8; ++mi) {
                const int n0 = mi * 16 + kq * 4;
                us4 ov;
#pragma unroll
                for (int r2 = 0; r2 < 4; ++r2)
                    ov[r2] = f2bf(acc[mi][3][r2]);
                *(us4*)&usW[4096 + mrow * 128 + (((n0 >> 3) ^ mrow) & 15) * 8 + (n0 & 7)] = ov;
            }
            FENCE();
#pragma unroll
            for (int ks = 0; ks < 4; ++ks)
                aV[ks] = *(const s8v*)&usW[4096 + mrow * 128 + (((ks * 4 + kq) ^ mrow) & 15) * 8];
#pragma unroll
            for (int eblk = 0; eblk < 2; ++eblk)
#pragma unroll
                for (int ks = 0; ks < 4; ++ks)
                    vk1[eblk] = __builtin_amdgcn_mfma_f32_16x16x32_bf16(
                        aV[ks], bK[eblk][ks], vk1[eblk], 0, 0, 0);
            // store the 33x32 partial (each (p,bh) slot written exactly once)
            const int hh = ((tN - 1024) >> 6) + wc;
            const int bh = (tM >> 12) * 32 + hh;
            const int p  = ((tM & 4095) >> 8) * 2 + wr;
            float* vb = vkp + ((size_t)p * 128 + bh) * 1056;
#pragma unroll
            for (int eblk = 0; eblk < 2; ++eblk) {
                const int e = eblk * 16 + mrow;
#pragma unroll
                for (int r = 0; r < 4; ++r) {
                    vb[(crow0 + r) * 32 + e]      = vk0[eblk][r];
                    vb[(16 + crow0 + r) * 32 + e] = vk1[eblk][r];
                }
                if (kq == 0) vb[1024 + e] = pd[eblk][0];
            }
        } else {
#pragma unroll
            for (int mi = 0; mi < 8; ++mi)
#pragma unroll
                for (int ni = 0; ni < 4; ++ni) {
                    const int row = tM + wr * 128 + mi * 16 + crow0;
                    const int col = tN + wc * 64 + ni * 16 + ccol;
#pragma unroll
                    for (int r2 = 0; r2 < 4; ++r2)
                        Cq[(size_t)(row + r2) * 1024 + col] =
                            f2bf(fmaxf(acc[mi][ni][r2], 0.f));
                }
        }
    } else {
#pragma unroll
        for (int mi = 0; mi < 8; ++mi)
#pragma unroll
            for (int ni = 0; ni < 4; ++ni) {
                const int row = tM + wr * 128 + mi * 16 + crow0;
                const int col = tN + wc * 64 + ni * 16 + ccol;
#pragma unroll
                for (int r2 = 0; r2 < 4; ++r2)
                    Cf[(size_t)(row + r2) * N + col] = acc[mi][ni][r2] + bias[col];
            }
    }
}

// XCD-aware tile map: xcd = blk&7 owns an 8-M-tile stripe; N swept in panels
// of 4 (B-panel 2 MB stays L2-hot), tN fastest within panel.
__device__ __forceinline__ void xcd_map256(int blk, int MT, int& tM, int& tN) {
    const int xcd = blk & 7;
    const int i   = blk >> 3;
    const int MTx = MT >> 3;             // M-tiles per XCD (8)
    const int ppan = MTx * 4;            // blocks per 4-wide panel per XCD
    const int p   = i / ppan;
    const int i2  = i % ppan;
    tM = (xcd * MTx + (i2 >> 2)) * 256;
    tN = (p * 4 + (i2 & 3)) * 256;
}

__global__ __launch_bounds__(512, 2)
void gemm_qkv(const unsigned short* __restrict__ A,
              const unsigned short* __restrict__ Bt,
              unsigned short* __restrict__ Cq, float* __restrict__ vkp,
              int M, int N) {
    extern __shared__ unsigned short lds[];
    int tM, tN;
    xcd_map256(blockIdx.x, M >> 8, tM, tN);
    gemm_core256<0>(A, Bt, Cq, vkp, nullptr, nullptr, N, tM, tN, lds);
}

__global__ __launch_bounds__(512, 2)
void gemm_proj(const unsigned short* __restrict__ A,
               const unsigned short* __restrict__ Bt,
               float* __restrict__ C, const float* __restrict__ bias,
               int M, int N) {
    extern __shared__ unsigned short lds[];
    int tM, tN;
    xcd_map256(blockIdx.x, M >> 8, tM, tN);
    gemm_core256<1>(A, Bt, nullptr, nullptr, C, bias, N, tM, tN, lds);
}

// --------------- y = (vk @ reluQ) / pad-row, MFMA K=32 ---------------------
__global__ __launch_bounds__(256)
void lite_apply(const unsigned short* __restrict__ qb,
                const float* __restrict__ vkp,
                unsigned short* __restrict__ yb) {
    const int bh = blockIdx.x, nb = blockIdx.y;
    const int b = bh >> 5, h = bh & 31;
    __shared__ unsigned short vkh[48 * 32];
    __shared__ unsigned short vkl[48 * 32];
    const int t = threadIdx.x;
    for (int i = t; i < 48 * 32; i += 256) {
        float v = 0.f;
        if (i < 33 * 32) {
#pragma unroll
            for (int p = 0; p < 32; ++p)
                v += vkp[((size_t)p * 128 + bh) * 1056 + i];
        }
        unsigned short hi = f2bf(v);
        vkh[i] = hi;
        vkl[i] = f2bf(v - bf2f(hi));
    }
    __syncthreads();

    const int lane = t & 63, wv = t >> 6;
    const int col = lane & 15, quad = lane >> 4;
    s8v b0h = *(const s8v*)&vkh[(col)      * 32 + quad * 8];
    s8v b0l = *(const s8v*)&vkl[(col)      * 32 + quad * 8];
    s8v b1h = *(const s8v*)&vkh[(16 + col) * 32 + quad * 8];
    s8v b1l = *(const s8v*)&vkl[(16 + col) * 32 + quad * 8];
    s8v b2h = *(const s8v*)&vkh[(32 + col) * 32 + quad * 8];
    s8v b2l = *(const s8v*)&vkl[(32 + col) * 32 + quad * 8];

    const int ntile = nb * 256 + wv * 64;
#pragma unroll
    for (int mi = 0; mi < 4; ++mi) {
        int tok = ntile + mi * 16 + col;
        const unsigned short* qp =
            qb + (size_t)(b * 4096 + tok) * 1024 + h * 32 + quad * 8;
        s8v a = *(const s8v*)qp;
        f32x4 n0 = {}, n1 = {}, dd = {};
        n0 = __builtin_amdgcn_mfma_f32_16x16x32_bf16(b0h, a, n0, 0, 0, 0);
        n0 = __builtin_amdgcn_mfma_f32_16x16x32_bf16(b0l, a, n0, 0, 0, 0);
        n1 = __builtin_amdgcn_mfma_f32_16x16x32_bf16(b1h, a, n1, 0, 0, 0);
        n1 = __builtin_amdgcn_mfma_f32_16x16x32_bf16(b1l, a, n1, 0, 0, 0);
        dd = __builtin_amdgcn_mfma_f32_16x16x32_bf16(b2h, a, dd, 0, 0, 0);
        dd = __builtin_amdgcn_mfma_f32_16x16x32_bf16(b2l, a, dd, 0, 0, 0);
        float den  = __shfl(dd[0], col, 64);
        float rinv = 1.f / (den + 1e-15f);
        us4 o0, o1;
#pragma unroll
        for (int r = 0; r < 4; ++r) {
            o0[r] = f2bf(n0[r] * rinv);
            o1[r] = f2bf(n1[r] * rinv);
        }
        size_t o = (size_t)(b * 4096 + tok) * 1024 + h * 32;
        *(us4*)&yb[o + quad * 4]      = o0;
        *(us4*)&yb[o + 16 + quad * 4] = o1;
    }
}

// ---------------------------------------------------------------------------
extern "C" void kernel_launch(void* const* d_in, const int* in_sizes, int n_in,
                              void* d_out, int out_size, void* d_ws, size_t ws_size,
                              hipStream_t stream) {
    const float* x     = (const float*)d_in[0];   // (4,4096,1024)
    const float* Wqkv  = (const float*)d_in[1];   // (3072,1024)
    const float* Wproj = (const float*)d_in[2];   // (1024,1024)
    const float* bproj = (const float*)d_in[3];   // (1024,)
    float* out = (float*)d_out;                   // (4,4096,1024) fp32

    const int M = 16384, Cdim = 1024, O1 = 3072;

    unsigned short* xb     = (unsigned short*)d_ws;
    unsigned short* wqkvb  = xb + (size_t)M * Cdim;               // permuted rows
    unsigned short* wprojb = wqkvb + (size_t)O1 * Cdim;
    unsigned short* qb     = wprojb + (size_t)Cdim * Cdim;        // Q token-major
    unsigned short* ybuf   = qb + (size_t)M * Cdim;
    float* vkp             = (float*)(ybuf + (size_t)M * Cdim);   // [32][128][1056]
    // ws use: ~121 MB (kvT eliminated)

    static int attr_done = 0;
    if (!attr_done) {
        hipFuncSetAttribute((const void*)gemm_qkv,
                            hipFuncAttributeMaxDynamicSharedMemorySize, 98304);
        hipFuncSetAttribute((const void*)gemm_proj,
                            hipFuncAttributeMaxDynamicSharedMemorySize, 98304);
        attr_done = 1;
    }

    const int PREP_GROUPS = (16777216 + 3145728 + 1048576) / 8;
    prep<<<(PREP_GROUPS + 255) / 256, 256, 0, stream>>>(
        x, Wqkv, Wproj, xb, wqkvb, wprojb);

    gemm_qkv<<<(M / 256) * (O1 / 256), 512, 98304, stream>>>(
        xb, wqkvb, qb, vkp, M, O1);

    lite_apply<<<dim3(128, 16), 256, 0, stream>>>(qb, vkp, ybuf);

    gemm_proj<<<(M / 256) * (Cdim / 256), 512, 98304, stream>>>(
        ybuf, wprojb, out, bproj, M, Cdim);
}